// Round 5
// baseline (3182.558 us; speedup 1.0000x reference)
//
#include <hip/hip_runtime.h>
#include <cstdint>

typedef unsigned short u16;
typedef __bf16 bf16x8 __attribute__((ext_vector_type(8)));
typedef unsigned short u16x8 __attribute__((ext_vector_type(8)));
typedef float f32x4 __attribute__((ext_vector_type(4)));

__device__ __forceinline__ float b2f(u16 u) { return __uint_as_float(((unsigned)u) << 16); }
__device__ __forceinline__ u16 f2b(float f) {
  unsigned u = __float_as_uint(f);
  return (u16)((u + 0x7FFFu + ((u >> 16) & 1u)) >> 16);
}

#define GLDS(g, l) __builtin_amdgcn_global_load_lds( \
    (const __attribute__((address_space(1))) void*)(g), \
    (__attribute__((address_space(3))) void*)(l), 16, 0, 0)

// ---------------- elementwise ----------------
__global__ __launch_bounds__(256) void addpe_kernel(const float* __restrict__ x,
                                                    const float* __restrict__ pe,
                                                    float* __restrict__ h) {
  int i = blockIdx.x * 256 + threadIdx.x;          // one float4 / thread
  float4 xv = ((const float4*)x)[i];
  float4 pv = ((const float4*)pe)[i & 0x1FFFF];    // S*D/4 = 131072
  float4 o;
  o.x = xv.x + pv.x; o.y = xv.y + pv.y; o.z = xv.z + pv.z; o.w = xv.w + pv.w;
  ((float4*)h)[i] = o;
}

__global__ __launch_bounds__(256) void copy_kernel(const float* __restrict__ h,
                                                   float* __restrict__ out) {
  int i = blockIdx.x * 256 + threadIdx.x;
  ((float4*)out)[i] = ((const float4*)h)[i];
}

__global__ __launch_bounds__(256) void bias_concat_kernel(const float* __restrict__ a,
                                                          const float* __restrict__ b,
                                                          const float* __restrict__ c,
                                                          float* __restrict__ o) {
  int i = blockIdx.x * 256 + threadIdx.x;  // 0..3071
  float v = (i < 1024) ? a[i] : ((i < 2048) ? b[i - 1024] : c[i - 2048]);
  o[i] = v;
}

// ---------------- layernorm (f32 in -> bf16 out), 1 block per row ----------------
__global__ __launch_bounds__(256) void ln_kernel(const float* __restrict__ in,
                                                 const float* __restrict__ g,
                                                 const float* __restrict__ bta,
                                                 u16* __restrict__ out) {
  int row = blockIdx.x, t = threadIdx.x;
  const float4 v = ((const float4*)(in + (size_t)row * 1024))[t];
  float s = v.x + v.y + v.z + v.w;
  float s2 = v.x * v.x + v.y * v.y + v.z * v.z + v.w * v.w;
#pragma unroll
  for (int off = 32; off > 0; off >>= 1) { s += __shfl_xor(s, off); s2 += __shfl_xor(s2, off); }
  __shared__ __align__(16) float red[8];
  int w = t >> 6;
  if ((t & 63) == 0) { red[w] = s; red[4 + w] = s2; }
  __syncthreads();
  s = red[0] + red[1] + red[2] + red[3];
  s2 = red[4] + red[5] + red[6] + red[7];
  float mu = s * (1.0f / 1024.0f);
  float var = s2 * (1.0f / 1024.0f) - mu * mu;
  float rstd = rsqrtf(var + 1e-6f);
  float4 gv = ((const float4*)g)[t];
  float4 bv = ((const float4*)bta)[t];
  ushort4 o;
  o.x = f2b((v.x - mu) * rstd * gv.x + bv.x);
  o.y = f2b((v.y - mu) * rstd * gv.y + bv.y);
  o.z = f2b((v.z - mu) * rstd * gv.z + bv.z);
  o.w = f2b((v.w - mu) * rstd * gv.w + bv.w);
  ((ushort4*)(out + (size_t)row * 1024))[t] = o;
}

// ---------------- weight transpose + f32->bf16: src[K][N] f32 -> dst[N][K] bf16 ----------------
__global__ __launch_bounds__(256) void transpose_kernel(const float* __restrict__ src,
                                                        u16* __restrict__ dst,
                                                        int K, int N) {
  __shared__ __align__(16) float tile[32][33];
  int n0 = blockIdx.x * 32, k0 = blockIdx.y * 32;
  int tx = threadIdx.x, ty = threadIdx.y;  // 32 x 8
#pragma unroll
  for (int j = 0; j < 4; j++)
    tile[ty + j * 8][tx] = src[(size_t)(k0 + ty + j * 8) * N + n0 + tx];
  __syncthreads();
#pragma unroll
  for (int j = 0; j < 4; j++)
    dst[(size_t)(n0 + ty + j * 8) * K + k0 + tx] = f2b(tile[tx][ty + j * 8]);
}

// ---------------- GEMM (256M x BN, 8 waves, 4-deep ring, fine-phased schedule) ----------------
// Per K-step two phases, each {ds_read batch || GLDS prefetch -> bar -> lgkmcnt(0)
// -> setprio(1) -> MFMA cluster -> setprio(0) -> bar}. Counted vmcnt (never 0 in
// steady state) once per K-step in phase 1. Loads/tile LPT = 4 (BN=256) or 3 (BN=128);
// steady-state wait = vmcnt(2*LPT) -> tile tt+1 landed, tiles tt+2/tt+3 in flight.
// Race-freedom: slot (tt+3)&3 == (tt-1)&3; tile tt-1's last ds_reads retire at its
// ph1 lgkmcnt(0), published by the closing barrier, before iteration tt's GLDS.
// LDS swizzle both-sides (rule #21): source column pre-swizzled, read slot XORed.
// EPI: 0 = bf16 out, 1 = gelu->bf16, 2 = Fo=R+v (f32), 3 = Fo=Fo+R+v (f32).
template <int EPI, int BN>
__global__ __launch_bounds__(512, 2) void gemm256(const u16* __restrict__ A,
                                                  const u16* __restrict__ Wt,
                                                  const float* __restrict__ bias,
                                                  u16* __restrict__ Cb,
                                                  const float* __restrict__ R,
                                                  float* __restrict__ Fo,
                                                  int M, int N, int K) {
  constexpr int NI = BN / 64;        // per-wave 16-col blocks (4 or 2)
  constexpr int BSLOT = BN * 32;     // u16 per B ring slot
  __shared__ __align__(16) u16 As[4 * 8192];   // 4 slots x [256][32] bf16
  __shared__ __align__(16) u16 Bs[4 * BSLOT];  // 4 slots x [BN][32] bf16
  int t = threadIdx.x;
  int lane = t & 63, w = t >> 6;
  int wm = w >> 2, wn = w & 3;                 // wave grid 2(M) x 4(N)
  int l15 = lane & 15, quad = lane >> 4;
  int m0 = blockIdx.y * 256, n0 = blockIdx.x * BN;

  // staging: thread t covers tile row (t>>2) (+128 for 2nd A GLDS), 16B slot (t&3)
  int swz = 8 * ((t & 3) ^ ((t >> 3) & 3));
  const u16* Ap = A + (size_t)(m0 + (t >> 2)) * K + swz;
  const u16* Bp = Wt + (size_t)(n0 + (t >> 2)) * K + swz;  // BN=128: t>>2 in 0..127
  u16* AsW = As + t * 8;
  u16* BsW = Bs + t * 8;

  int slotr = 8 * (quad ^ ((l15 >> 1) & 3));   // swizzled read slot (same involution)
  f32x4 acc[8][NI] = {};
  int nt = K >> 5;

  // prologue: issue tiles 0,1,2 into slots 0,1,2
#pragma unroll
  for (int pp = 0; pp < 3; ++pp) {
    GLDS(Ap, AsW + pp * 8192);
    GLDS(Ap + (size_t)128 * K, AsW + pp * 8192 + 4096);
    GLDS(Bp, BsW + pp * BSLOT);
    if constexpr (BN == 256) GLDS(Bp + (size_t)128 * K, BsW + pp * BSLOT + 4096);
    Ap += 32; Bp += 32;
  }
  if constexpr (BN == 256) asm volatile("s_waitcnt vmcnt(8)" : : : "memory");
  else                     asm volatile("s_waitcnt vmcnt(6)" : : : "memory");
  __builtin_amdgcn_sched_barrier(0);
  __builtin_amdgcn_s_barrier();

  for (int tt = 0; tt < nt; ++tt) {
    const u16* Ab = As + (tt & 3) * 8192;
    const u16* Bb = Bs + (tt & 3) * BSLOT;
    bool pf = (tt + 3 < nt);
    int asl = ((tt + 3) & 3) * 8192;
    int bsl = ((tt + 3) & 3) * BSLOT;

    // ---- phase 0: ds_read A(mi0..3) + B(all) || A-prefetch; MFMA mi 0..3 ----
    bf16x8 a0[4], bfr[NI];
#pragma unroll
    for (int mi = 0; mi < 4; mi++)
      a0[mi] = *(const bf16x8*)(Ab + (wm * 128 + mi * 16 + l15) * 32 + slotr);
#pragma unroll
    for (int ni = 0; ni < NI; ni++)
      bfr[ni] = *(const bf16x8*)(Bb + (wn * (NI * 16) + ni * 16 + l15) * 32 + slotr);
    if (pf) { GLDS(Ap, AsW + asl); GLDS(Ap + (size_t)128 * K, AsW + asl + 4096); Ap += 32; }
    __builtin_amdgcn_sched_barrier(0);
    __builtin_amdgcn_s_barrier();
    asm volatile("s_waitcnt lgkmcnt(0)" : : : "memory");
    __builtin_amdgcn_sched_barrier(0);
    __builtin_amdgcn_s_setprio(1);
#pragma unroll
    for (int mi = 0; mi < 4; mi++)
#pragma unroll
      for (int ni = 0; ni < NI; ni++)
        acc[mi][ni] = __builtin_amdgcn_mfma_f32_16x16x32_bf16(a0[mi], bfr[ni], acc[mi][ni], 0, 0, 0);
    __builtin_amdgcn_s_setprio(0);
    __builtin_amdgcn_sched_barrier(0);
    __builtin_amdgcn_s_barrier();

    // ---- phase 1: ds_read A(mi4..7) || B-prefetch; counted vmcnt; MFMA mi 4..7 ----
    bf16x8 a1[4];
#pragma unroll
    for (int mi = 0; mi < 4; mi++)
      a1[mi] = *(const bf16x8*)(Ab + (wm * 128 + (mi + 4) * 16 + l15) * 32 + slotr);
    if (pf) {
      GLDS(Bp, BsW + bsl);
      if constexpr (BN == 256) GLDS(Bp + (size_t)128 * K, BsW + bsl + 4096);
      Bp += 32;
    }
    // wait for tile tt+1 (needed by next iteration's ph0); never 0 in steady state
    if (tt + 4 <= nt) {
      if constexpr (BN == 256) asm volatile("s_waitcnt vmcnt(8)" : : : "memory");
      else                     asm volatile("s_waitcnt vmcnt(6)" : : : "memory");
    } else if (tt + 3 == nt) {
      if constexpr (BN == 256) asm volatile("s_waitcnt vmcnt(4)" : : : "memory");
      else                     asm volatile("s_waitcnt vmcnt(3)" : : : "memory");
    } else if (tt + 2 == nt) {
      asm volatile("s_waitcnt vmcnt(0)" : : : "memory");
    }
    __builtin_amdgcn_sched_barrier(0);
    __builtin_amdgcn_s_barrier();
    asm volatile("s_waitcnt lgkmcnt(0)" : : : "memory");
    __builtin_amdgcn_sched_barrier(0);
    __builtin_amdgcn_s_setprio(1);
#pragma unroll
    for (int mi = 0; mi < 4; mi++)
#pragma unroll
      for (int ni = 0; ni < NI; ni++)
        acc[mi + 4][ni] = __builtin_amdgcn_mfma_f32_16x16x32_bf16(a1[mi], bfr[ni], acc[mi + 4][ni], 0, 0, 0);
    __builtin_amdgcn_s_setprio(0);
    __builtin_amdgcn_sched_barrier(0);
    __builtin_amdgcn_s_barrier();
  }

  int cm = m0 + wm * 128, cn = n0 + wn * (NI * 16);
  int rq = quad * 4, cq = l15;
#pragma unroll
  for (int ni = 0; ni < NI; ni++) {
    int col = cn + ni * 16 + cq;
    float bv = bias[col];
#pragma unroll
    for (int mi = 0; mi < 8; mi++) {
      int row = cm + mi * 16 + rq;
#pragma unroll
      for (int rr = 0; rr < 4; rr++) {
        size_t idx = (size_t)(row + rr) * N + col;
        float v = acc[mi][ni][rr] + bv;
        if constexpr (EPI == 0) {
          Cb[idx] = f2b(v);
        } else if constexpr (EPI == 1) {
          Cb[idx] = f2b(0.5f * v * (1.0f + erff(v * 0.70710678118f)));
        } else if constexpr (EPI == 2) {
          Fo[idx] = R[idx] + v;
        } else {
          Fo[idx] = Fo[idx] + R[idx] + v;
        }
      }
    }
  }
}

// ---------------- MFMA flash attention w/ relative position bias ----------------
__global__ __launch_bounds__(256) void attn_mfma(const u16* __restrict__ Qg,
                                                 const u16* __restrict__ Kg,
                                                 const u16* __restrict__ Vg,
                                                 const float* __restrict__ bt,
                                                 u16* __restrict__ ctx,
                                                 int rs) {
  __shared__ __align__(16) u16 Qs[64 * 72];
  __shared__ __align__(16) u16 Ks[128 * 72];
  __shared__ __align__(16) u16 Vts[64 * 136];
  __shared__ __align__(16) u16 Ps[64 * 136];
  __shared__ __align__(16) u16 bias_s[1023];
  int t = threadIdx.x, w = t >> 6, lane = t & 63;
  int l15 = lane & 15, quad = lane >> 4;
  int q0 = blockIdx.x * 64, h = blockIdx.y, b = blockIdx.z;
  size_t base = ((size_t)b * 512) * rs + (size_t)h * 64;  // + s*rs + d

  {  // stage Q (64 rows x 64 d)
    int r = t >> 3, c = (t & 7) * 8;
    *(u16x8*)(Qs + r * 72 + c) = *(const u16x8*)(Qg + base + (size_t)(q0 + r) * rs + c);
    *(u16x8*)(Qs + (r + 32) * 72 + c) = *(const u16x8*)(Qg + base + (size_t)(q0 + r + 32) * rs + c);
  }
  for (int e = t; e < 1023; e += 256) bias_s[e] = f2b(bt[e * 16 + h]);

  float m_st[4], l_st[4];
  f32x4 O[4] = {};
#pragma unroll
  for (int i = 0; i < 4; i++) { m_st[i] = -1e30f; l_st[i] = 0.f; }

  __syncthreads();
  bf16x8 aq0 = *(const bf16x8*)(Qs + (w * 16 + l15) * 72 + quad * 8);
  bf16x8 aq1 = *(const bf16x8*)(Qs + (w * 16 + l15) * 72 + 32 + quad * 8);

  for (int kt = 0; kt < 4; kt++) {
    if (kt) __syncthreads();
    {  // stage K tile (128 rows x 64 d)
      int r = t >> 3, c = (t & 7) * 8;
#pragma unroll
      for (int p = 0; p < 4; p++)
        *(u16x8*)(Ks + (p * 32 + r) * 72 + c) =
            *(const u16x8*)(Kg + base + (size_t)(kt * 128 + p * 32 + r) * rs + c);
    }
    {  // stage V transposed: Vts[d][k]
#pragma unroll
      for (int p = 0; p < 4; p++) {
        u16x8 vv;
        int k8 = kt * 128 + p * 32 + w * 8;
#pragma unroll
        for (int j = 0; j < 8; j++) vv[j] = Vg[base + (size_t)(k8 + j) * rs + lane];
        *(u16x8*)(Vts + lane * 136 + p * 32 + w * 8) = vv;
      }
    }
    __syncthreads();

    f32x4 sc[8];
#pragma unroll
    for (int nt = 0; nt < 8; nt++) {
      bf16x8 bk0 = *(const bf16x8*)(Ks + (nt * 16 + l15) * 72 + quad * 8);
      bf16x8 bk1 = *(const bf16x8*)(Ks + (nt * 16 + l15) * 72 + 32 + quad * 8);
      f32x4 z = {};
      z = __builtin_amdgcn_mfma_f32_16x16x32_bf16(aq0, bk0, z, 0, 0, 0);
      sc[nt] = __builtin_amdgcn_mfma_f32_16x16x32_bf16(aq1, bk1, z, 0, 0, 0);
    }
#pragma unroll
    for (int nt = 0; nt < 8; nt++) {
      int kg = kt * 128 + nt * 16 + l15;
#pragma unroll
      for (int rr = 0; rr < 4; rr++) {
        int qg = q0 + w * 16 + quad * 4 + rr;
        sc[nt][rr] = sc[nt][rr] * 0.125f + b2f(bias_s[qg - kg + 511]);
      }
    }
#pragma unroll
    for (int rr = 0; rr < 4; rr++) {
      float mt = sc[0][rr];
#pragma unroll
      for (int nt = 1; nt < 8; nt++) mt = fmaxf(mt, sc[nt][rr]);
#pragma unroll
      for (int off = 8; off > 0; off >>= 1) mt = fmaxf(mt, __shfl_xor(mt, off));
      float mnew = fmaxf(m_st[rr], mt);
      float alpha = __expf(m_st[rr] - mnew);
      float ps = 0.f;
#pragma unroll
      for (int nt = 0; nt < 8; nt++) {
        float p = __expf(sc[nt][rr] - mnew);
        sc[nt][rr] = p;
        ps += p;
      }
#pragma unroll
      for (int off = 8; off > 0; off >>= 1) ps += __shfl_xor(ps, off);
      m_st[rr] = mnew;
      l_st[rr] = l_st[rr] * alpha + ps;
#pragma unroll
      for (int dt = 0; dt < 4; dt++) O[dt][rr] *= alpha;
#pragma unroll
      for (int nt = 0; nt < 8; nt++)
        Ps[(w * 16 + quad * 4 + rr) * 136 + nt * 16 + l15] = f2b(sc[nt][rr]);
    }
#pragma unroll
    for (int ks = 0; ks < 4; ks++) {
      bf16x8 ap = *(const bf16x8*)(Ps + (w * 16 + l15) * 136 + ks * 32 + quad * 8);
#pragma unroll
      for (int dt = 0; dt < 4; dt++) {
        bf16x8 bv = *(const bf16x8*)(Vts + (dt * 16 + l15) * 136 + ks * 32 + quad * 8);
        O[dt] = __builtin_amdgcn_mfma_f32_16x16x32_bf16(ap, bv, O[dt], 0, 0, 0);
      }
    }
  }
#pragma unroll
  for (int dt = 0; dt < 4; dt++) {
    int col = h * 64 + dt * 16 + l15;
#pragma unroll
    for (int rr = 0; rr < 4; rr++) {
      int row = q0 + w * 16 + quad * 4 + rr;
      ctx[((size_t)b * 512 + row) * 1024 + col] = f2b(O[dt][rr] / l_st[rr]);
    }
  }
}

// ---------------- driver ----------------
extern "C" void kernel_launch(void* const* d_in, const int* in_sizes, int n_in,
                              void* d_out, int out_size, void* d_ws, size_t ws_size,
                              hipStream_t stream) {
  (void)in_sizes; (void)n_in; (void)out_size; (void)ws_size;
  const float* x = (const float*)d_in[0];
  const float* pe = (const float*)d_in[1];
  const float* wq = (const float*)d_in[2];
  const float* bq = (const float*)d_in[3];
  const float* wk = (const float*)d_in[4];
  const float* bk = (const float*)d_in[5];
  const float* wv = (const float*)d_in[6];
  const float* bvv = (const float*)d_in[7];
  const float* wo = (const float*)d_in[8];
  const float* bo = (const float*)d_in[9];
  const float* btab = (const float*)d_in[10];
  const float* w1 = (const float*)d_in[11];
  const float* b1 = (const float*)d_in[12];
  const float* w2 = (const float*)d_in[13];
  const float* b2 = (const float*)d_in[14];
  const float* ln1g = (const float*)d_in[15];
  const float* ln1b = (const float*)d_in[16];
  const float* ln2g = (const float*)d_in[17];
  const float* ln2b = (const float*)d_in[18];

  const int M = 8192, D = 1024, F = 4096, NQKV = 3072;
  char* p = (char*)d_ws;
  float* h = (float*)p;   p += (size_t)M * D * 4;        // 32 MB
  float* o1 = (float*)p;  p += (size_t)M * D * 4;        // 32 MB
  u16* xn = (u16*)p;      p += (size_t)M * D * 2;        // 16 MB
  u16* qkv = (u16*)p;     p += (size_t)M * NQKV * 2;     // 48 MB
  u16* ctx = (u16*)p;     p += (size_t)M * D * 2;        // 16 MB
  u16* mid = qkv;  // aliases qkv..ctx (64 MB); qkv/ctx dead by the time mid is written
  u16* wqkvt = (u16*)p;   p += (size_t)NQKV * D * 2;     // 6 MB
  u16* wto = (u16*)p;     p += (size_t)D * D * 2;        // 2 MB
  u16* wt2 = wqkvt;  // aliases wqkvt+wto (exactly 8 MB); both dead after O-proj
  u16* wt1 = (u16*)p;     p += (size_t)D * F * 2;        // 8 MB
  float* bqkv = (float*)p; p += (size_t)NQKV * 4;        // 12 KB

  addpe_kernel<<<8192, 256, 0, stream>>>(x, pe, h);
  for (int i = 0; i < 6; i++) {
    ln_kernel<<<M, 256, 0, stream>>>(h, ln1g + i * D, ln1b + i * D, xn);
    transpose_kernel<<<dim3(D / 32, D / 32), dim3(32, 8), 0, stream>>>(wq + (size_t)i * D * D, wqkvt, D, D);
    transpose_kernel<<<dim3(D / 32, D / 32), dim3(32, 8), 0, stream>>>(wk + (size_t)i * D * D, wqkvt + (size_t)D * D, D, D);
    transpose_kernel<<<dim3(D / 32, D / 32), dim3(32, 8), 0, stream>>>(wv + (size_t)i * D * D, wqkvt + (size_t)2 * D * D, D, D);
    transpose_kernel<<<dim3(D / 32, D / 32), dim3(32, 8), 0, stream>>>(wo + (size_t)i * D * D, wto, D, D);
    transpose_kernel<<<dim3(F / 32, D / 32), dim3(32, 8), 0, stream>>>(w1 + (size_t)i * D * F, wt1, D, F);
    bias_concat_kernel<<<12, 256, 0, stream>>>(bq + i * D, bk + i * D, bvv + i * D, bqkv);
    // QKV fused: M=8192, N=3072, K=1024 (384 blocks)
    gemm256<0, 256><<<dim3(NQKV / 256, M / 256), 512, 0, stream>>>(xn, wqkvt, bqkv, qkv, nullptr, nullptr, M, NQKV, D);
    attn_mfma<<<dim3(8, 16, 16), 256, 0, stream>>>(qkv, qkv + D, qkv + 2 * D,
                                                   btab + (size_t)i * 1023 * 16, ctx, NQKV);
    // O-proj: N=1024 -> 256M x 128N tile, 256 blocks; o1 = h + ctx@wo + bo
    gemm256<2, 128><<<dim3(D / 128, M / 256), 512, 0, stream>>>(ctx, wto, bo + i * D, nullptr, h, o1, M, D, D);
    transpose_kernel<<<dim3(D / 32, F / 32), dim3(32, 8), 0, stream>>>(w2 + (size_t)i * F * D, wt2, F, D);
    ln_kernel<<<M, 256, 0, stream>>>(o1, ln2g + i * D, ln2b + i * D, xn);
    // FFN1: M=8192, N=4096, K=1024 (512 blocks, fused GELU)
    gemm256<1, 256><<<dim3(F / 256, M / 256), 512, 0, stream>>>(xn, wt1, b1 + i * F, mid, nullptr, nullptr, M, F, D);
    // FFN2: N=1024, K=4096 -> 256M x 128N tile, 256 blocks; h = h + o1 + ffn
    gemm256<3, 128><<<dim3(D / 128, M / 256), 512, 0, stream>>>(mid, wt2, b2 + i * D, nullptr, o1, h, M, D, F);
  }
  copy_kernel<<<8192, 256, 0, stream>>>(h, (float*)d_out);
}

// Round 6
// 2949.345 us; speedup vs baseline: 1.0791x; 1.0791x over previous
//
#include <hip/hip_runtime.h>
#include <cstdint>

typedef unsigned short u16;
typedef __bf16 bf16x8 __attribute__((ext_vector_type(8)));
typedef unsigned short u16x8 __attribute__((ext_vector_type(8)));
typedef float f32x4 __attribute__((ext_vector_type(4)));

__device__ __forceinline__ float b2f(u16 u) { return __uint_as_float(((unsigned)u) << 16); }
__device__ __forceinline__ u16 f2b(float f) {
  unsigned u = __float_as_uint(f);
  return (u16)((u + 0x7FFFu + ((u >> 16) & 1u)) >> 16);
}

#define GLDS(g, l) __builtin_amdgcn_global_load_lds( \
    (const __attribute__((address_space(1))) void*)(g), \
    (__attribute__((address_space(3))) void*)(l), 16, 0, 0)

// ---------------- elementwise ----------------
__global__ __launch_bounds__(256) void addpe_kernel(const float* __restrict__ x,
                                                    const float* __restrict__ pe,
                                                    float* __restrict__ h) {
  int i = blockIdx.x * 256 + threadIdx.x;          // one float4 / thread
  float4 xv = ((const float4*)x)[i];
  float4 pv = ((const float4*)pe)[i & 0x1FFFF];    // S*D/4 = 131072
  float4 o;
  o.x = xv.x + pv.x; o.y = xv.y + pv.y; o.z = xv.z + pv.z; o.w = xv.w + pv.w;
  ((float4*)h)[i] = o;
}

__global__ __launch_bounds__(256) void copy_kernel(const float* __restrict__ h,
                                                   float* __restrict__ out) {
  int i = blockIdx.x * 256 + threadIdx.x;
  ((float4*)out)[i] = ((const float4*)h)[i];
}

__global__ __launch_bounds__(256) void bias_concat_kernel(const float* __restrict__ a,
                                                          const float* __restrict__ b,
                                                          const float* __restrict__ c,
                                                          float* __restrict__ o) {
  int i = blockIdx.x * 256 + threadIdx.x;  // 0..3071
  float v = (i < 1024) ? a[i] : ((i < 2048) ? b[i - 1024] : c[i - 2048]);
  o[i] = v;
}

// ---------------- layernorm (f32 in -> bf16 out), 1 block per row ----------------
__global__ __launch_bounds__(256) void ln_kernel(const float* __restrict__ in,
                                                 const float* __restrict__ g,
                                                 const float* __restrict__ bta,
                                                 u16* __restrict__ out) {
  int row = blockIdx.x, t = threadIdx.x;
  const float4 v = ((const float4*)(in + (size_t)row * 1024))[t];
  float s = v.x + v.y + v.z + v.w;
  float s2 = v.x * v.x + v.y * v.y + v.z * v.z + v.w * v.w;
#pragma unroll
  for (int off = 32; off > 0; off >>= 1) { s += __shfl_xor(s, off); s2 += __shfl_xor(s2, off); }
  __shared__ __align__(16) float red[8];
  int w = t >> 6;
  if ((t & 63) == 0) { red[w] = s; red[4 + w] = s2; }
  __syncthreads();
  s = red[0] + red[1] + red[2] + red[3];
  s2 = red[4] + red[5] + red[6] + red[7];
  float mu = s * (1.0f / 1024.0f);
  float var = s2 * (1.0f / 1024.0f) - mu * mu;
  float rstd = rsqrtf(var + 1e-6f);
  float4 gv = ((const float4*)g)[t];
  float4 bv = ((const float4*)bta)[t];
  ushort4 o;
  o.x = f2b((v.x - mu) * rstd * gv.x + bv.x);
  o.y = f2b((v.y - mu) * rstd * gv.y + bv.y);
  o.z = f2b((v.z - mu) * rstd * gv.z + bv.z);
  o.w = f2b((v.w - mu) * rstd * gv.w + bv.w);
  ((ushort4*)(out + (size_t)row * 1024))[t] = o;
}

// ---------------- weight transpose + f32->bf16: src[K][N] f32 -> dst[N][K] bf16 ----------------
__global__ __launch_bounds__(256) void transpose_kernel(const float* __restrict__ src,
                                                        u16* __restrict__ dst,
                                                        int K, int N) {
  __shared__ __align__(16) float tile[32][33];
  int n0 = blockIdx.x * 32, k0 = blockIdx.y * 32;
  int tx = threadIdx.x, ty = threadIdx.y;  // 32 x 8
#pragma unroll
  for (int j = 0; j < 4; j++)
    tile[ty + j * 8][tx] = src[(size_t)(k0 + ty + j * 8) * N + n0 + tx];
  __syncthreads();
#pragma unroll
  for (int j = 0; j < 4; j++)
    dst[(size_t)(n0 + ty + j * 8) * K + k0 + tx] = f2b(tile[tx][ty + j * 8]);
}

// ---------------- GEMM (256M x BN, 8 waves, 4-deep ring, fine-phased schedule) ----------------
// Schedule identical to round-2 (verified): per K-step two phases, each {ds_read
// batch || GLDS prefetch -> bar -> lgkmcnt(0) -> setprio(1) -> MFMA -> setprio(0)
// -> bar}; counted vmcnt (never 0 in steady state) once per K-step in phase 1.
// Round-6 changes (no sync-structure edit):
//  (a) bijective XCD swizzle (requires gridDim.y % 8 == 0): XCD = linear_id & 7
//      selects the m-stripe, so blocks sharing an A-panel co-reside on one XCD
//      -> A fetched ~once chip-wide (was ~5x, FETCH 321 MB vs 136 compulsory).
//  (b) BN=128 wave grid 4M x 2N (per-wave 64x64): LDS read volume per K-step
//      96 KB -> 64 KB (A shared 2x not 4x). BN=256 path bit-identical to before.
// EPI: 0 = bf16 out, 1 = gelu->bf16, 2 = Fo=R+v (f32), 3 = Fo=Fo+R+v (f32).
template <int EPI, int BN>
__global__ __launch_bounds__(512, 2) void gemm256(const u16* __restrict__ A,
                                                  const u16* __restrict__ Wt,
                                                  const float* __restrict__ bias,
                                                  u16* __restrict__ Cb,
                                                  const float* __restrict__ R,
                                                  float* __restrict__ Fo,
                                                  int M, int N, int K) {
  constexpr int GM = (BN == 256) ? 2 : 4;      // wave grid GM(M) x GN(N)
  constexpr int GN = 8 / GM;
  constexpr int MI = 256 / (16 * GM);          // per-wave 16-row blocks (8 or 4)
  constexpr int NI = BN / (16 * GN);           // per-wave 16-col blocks (4)
  constexpr int MH = MI / 2;                   // per-phase m-blocks (4 or 2)
  constexpr int BSLOT = BN * 32;               // u16 per B ring slot
  __shared__ __align__(16) u16 As[4 * 8192];   // 4 slots x [256][32] bf16
  __shared__ __align__(16) u16 Bs[4 * BSLOT];  // 4 slots x [BN][32] bf16
  int t = threadIdx.x;
  int lane = t & 63, w = t >> 6;
  int wm, wn;
  if constexpr (BN == 256) { wm = w >> 2; wn = w & 3; }
  else                     { wm = w >> 1; wn = w & 1; }
  int l15 = lane & 15, quad = lane >> 4;

  // bijective XCD swizzle (m204-style); all launches have gridDim.y % 8 == 0
  int gx = gridDim.x;
  int li = blockIdx.y * gx + blockIdx.x;
  int sx = li >> 3;
  int rr_ = sx / gx;
  int by = (li & 7) * (gridDim.y >> 3) + rr_;
  int bx = sx - rr_ * gx;
  int m0 = by * 256, n0 = bx * BN;

  // staging: thread t covers tile row (t>>2) (+128 for 2nd A GLDS), 16B slot (t&3)
  int swz = 8 * ((t & 3) ^ ((t >> 3) & 3));
  const u16* Ap = A + (size_t)(m0 + (t >> 2)) * K + swz;
  const u16* Bp = Wt + (size_t)(n0 + (t >> 2)) * K + swz;  // BN=128: t>>2 in 0..127
  u16* AsW = As + t * 8;
  u16* BsW = Bs + t * 8;

  int slotr = 8 * (quad ^ ((l15 >> 1) & 3));   // swizzled read slot (same involution)
  f32x4 acc[MI][NI] = {};
  int nt = K >> 5;

  // prologue: issue tiles 0,1,2 into slots 0,1,2
#pragma unroll
  for (int pp = 0; pp < 3; ++pp) {
    GLDS(Ap, AsW + pp * 8192);
    GLDS(Ap + (size_t)128 * K, AsW + pp * 8192 + 4096);
    GLDS(Bp, BsW + pp * BSLOT);
    if constexpr (BN == 256) GLDS(Bp + (size_t)128 * K, BsW + pp * BSLOT + 4096);
    Ap += 32; Bp += 32;
  }
  if constexpr (BN == 256) asm volatile("s_waitcnt vmcnt(8)" : : : "memory");
  else                     asm volatile("s_waitcnt vmcnt(6)" : : : "memory");
  __builtin_amdgcn_sched_barrier(0);
  __builtin_amdgcn_s_barrier();

  for (int tt = 0; tt < nt; ++tt) {
    const u16* Ab = As + (tt & 3) * 8192;
    const u16* Bb = Bs + (tt & 3) * BSLOT;
    bool pf = (tt + 3 < nt);
    int asl = ((tt + 3) & 3) * 8192;
    int bsl = ((tt + 3) & 3) * BSLOT;

    // ---- phase 0: ds_read A(first half) + B(all) || A-prefetch; MFMA mi 0..MH ----
    bf16x8 a0[MH], bfr[NI];
#pragma unroll
    for (int mi = 0; mi < MH; mi++)
      a0[mi] = *(const bf16x8*)(Ab + (wm * (MI * 16) + mi * 16 + l15) * 32 + slotr);
#pragma unroll
    for (int ni = 0; ni < NI; ni++)
      bfr[ni] = *(const bf16x8*)(Bb + (wn * (NI * 16) + ni * 16 + l15) * 32 + slotr);
    if (pf) { GLDS(Ap, AsW + asl); GLDS(Ap + (size_t)128 * K, AsW + asl + 4096); Ap += 32; }
    __builtin_amdgcn_sched_barrier(0);
    __builtin_amdgcn_s_barrier();
    asm volatile("s_waitcnt lgkmcnt(0)" : : : "memory");
    __builtin_amdgcn_sched_barrier(0);
    __builtin_amdgcn_s_setprio(1);
#pragma unroll
    for (int mi = 0; mi < MH; mi++)
#pragma unroll
      for (int ni = 0; ni < NI; ni++)
        acc[mi][ni] = __builtin_amdgcn_mfma_f32_16x16x32_bf16(a0[mi], bfr[ni], acc[mi][ni], 0, 0, 0);
    __builtin_amdgcn_s_setprio(0);
    __builtin_amdgcn_sched_barrier(0);
    __builtin_amdgcn_s_barrier();

    // ---- phase 1: ds_read A(second half) || B-prefetch; counted vmcnt; MFMA mi MH.. ----
    bf16x8 a1[MH];
#pragma unroll
    for (int mi = 0; mi < MH; mi++)
      a1[mi] = *(const bf16x8*)(Ab + (wm * (MI * 16) + (mi + MH) * 16 + l15) * 32 + slotr);
    if (pf) {
      GLDS(Bp, BsW + bsl);
      if constexpr (BN == 256) GLDS(Bp + (size_t)128 * K, BsW + bsl + 4096);
      Bp += 32;
    }
    // wait for tile tt+1 (needed by next iteration's ph0); never 0 in steady state
    if (tt + 4 <= nt) {
      if constexpr (BN == 256) asm volatile("s_waitcnt vmcnt(8)" : : : "memory");
      else                     asm volatile("s_waitcnt vmcnt(6)" : : : "memory");
    } else if (tt + 3 == nt) {
      if constexpr (BN == 256) asm volatile("s_waitcnt vmcnt(4)" : : : "memory");
      else                     asm volatile("s_waitcnt vmcnt(3)" : : : "memory");
    } else if (tt + 2 == nt) {
      asm volatile("s_waitcnt vmcnt(0)" : : : "memory");
    }
    __builtin_amdgcn_sched_barrier(0);
    __builtin_amdgcn_s_barrier();
    asm volatile("s_waitcnt lgkmcnt(0)" : : : "memory");
    __builtin_amdgcn_sched_barrier(0);
    __builtin_amdgcn_s_setprio(1);
#pragma unroll
    for (int mi = 0; mi < MH; mi++)
#pragma unroll
      for (int ni = 0; ni < NI; ni++)
        acc[mi + MH][ni] = __builtin_amdgcn_mfma_f32_16x16x32_bf16(a1[mi], bfr[ni], acc[mi + MH][ni], 0, 0, 0);
    __builtin_amdgcn_s_setprio(0);
    __builtin_amdgcn_sched_barrier(0);
    __builtin_amdgcn_s_barrier();
  }

  int cm = m0 + wm * (MI * 16), cn = n0 + wn * (NI * 16);
  int rq = quad * 4, cq = l15;
#pragma unroll
  for (int ni = 0; ni < NI; ni++) {
    int col = cn + ni * 16 + cq;
    float bv = bias[col];
#pragma unroll
    for (int mi = 0; mi < MI; mi++) {
      int row = cm + mi * 16 + rq;
#pragma unroll
      for (int rr = 0; rr < 4; rr++) {
        size_t idx = (size_t)(row + rr) * N + col;
        float v = acc[mi][ni][rr] + bv;
        if constexpr (EPI == 0) {
          Cb[idx] = f2b(v);
        } else if constexpr (EPI == 1) {
          Cb[idx] = f2b(0.5f * v * (1.0f + erff(v * 0.70710678118f)));
        } else if constexpr (EPI == 2) {
          Fo[idx] = R[idx] + v;
        } else {
          Fo[idx] = Fo[idx] + R[idx] + v;
        }
      }
    }
  }
}

// ---------------- MFMA flash attention w/ relative position bias ----------------
__global__ __launch_bounds__(256) void attn_mfma(const u16* __restrict__ Qg,
                                                 const u16* __restrict__ Kg,
                                                 const u16* __restrict__ Vg,
                                                 const float* __restrict__ bt,
                                                 u16* __restrict__ ctx,
                                                 int rs) {
  __shared__ __align__(16) u16 Qs[64 * 72];
  __shared__ __align__(16) u16 Ks[128 * 72];
  __shared__ __align__(16) u16 Vts[64 * 136];
  __shared__ __align__(16) u16 Ps[64 * 136];
  __shared__ __align__(16) u16 bias_s[1023];
  int t = threadIdx.x, w = t >> 6, lane = t & 63;
  int l15 = lane & 15, quad = lane >> 4;
  int q0 = blockIdx.x * 64, h = blockIdx.y, b = blockIdx.z;
  size_t base = ((size_t)b * 512) * rs + (size_t)h * 64;  // + s*rs + d

  {  // stage Q (64 rows x 64 d)
    int r = t >> 3, c = (t & 7) * 8;
    *(u16x8*)(Qs + r * 72 + c) = *(const u16x8*)(Qg + base + (size_t)(q0 + r) * rs + c);
    *(u16x8*)(Qs + (r + 32) * 72 + c) = *(const u16x8*)(Qg + base + (size_t)(q0 + r + 32) * rs + c);
  }
  for (int e = t; e < 1023; e += 256) bias_s[e] = f2b(bt[e * 16 + h]);

  float m_st[4], l_st[4];
  f32x4 O[4] = {};
#pragma unroll
  for (int i = 0; i < 4; i++) { m_st[i] = -1e30f; l_st[i] = 0.f; }

  __syncthreads();
  bf16x8 aq0 = *(const bf16x8*)(Qs + (w * 16 + l15) * 72 + quad * 8);
  bf16x8 aq1 = *(const bf16x8*)(Qs + (w * 16 + l15) * 72 + 32 + quad * 8);

  for (int kt = 0; kt < 4; kt++) {
    if (kt) __syncthreads();
    {  // stage K tile (128 rows x 64 d)
      int r = t >> 3, c = (t & 7) * 8;
#pragma unroll
      for (int p = 0; p < 4; p++)
        *(u16x8*)(Ks + (p * 32 + r) * 72 + c) =
            *(const u16x8*)(Kg + base + (size_t)(kt * 128 + p * 32 + r) * rs + c);
    }
    {  // stage V transposed: Vts[d][k]
#pragma unroll
      for (int p = 0; p < 4; p++) {
        u16x8 vv;
        int k8 = kt * 128 + p * 32 + w * 8;
#pragma unroll
        for (int j = 0; j < 8; j++) vv[j] = Vg[base + (size_t)(k8 + j) * rs + lane];
        *(u16x8*)(Vts + lane * 136 + p * 32 + w * 8) = vv;
      }
    }
    __syncthreads();

    f32x4 sc[8];
#pragma unroll
    for (int nt = 0; nt < 8; nt++) {
      bf16x8 bk0 = *(const bf16x8*)(Ks + (nt * 16 + l15) * 72 + quad * 8);
      bf16x8 bk1 = *(const bf16x8*)(Ks + (nt * 16 + l15) * 72 + 32 + quad * 8);
      f32x4 z = {};
      z = __builtin_amdgcn_mfma_f32_16x16x32_bf16(aq0, bk0, z, 0, 0, 0);
      sc[nt] = __builtin_amdgcn_mfma_f32_16x16x32_bf16(aq1, bk1, z, 0, 0, 0);
    }
#pragma unroll
    for (int nt = 0; nt < 8; nt++) {
      int kg = kt * 128 + nt * 16 + l15;
#pragma unroll
      for (int rr = 0; rr < 4; rr++) {
        int qg = q0 + w * 16 + quad * 4 + rr;
        sc[nt][rr] = sc[nt][rr] * 0.125f + b2f(bias_s[qg - kg + 511]);
      }
    }
#pragma unroll
    for (int rr = 0; rr < 4; rr++) {
      float mt = sc[0][rr];
#pragma unroll
      for (int nt = 1; nt < 8; nt++) mt = fmaxf(mt, sc[nt][rr]);
#pragma unroll
      for (int off = 8; off > 0; off >>= 1) mt = fmaxf(mt, __shfl_xor(mt, off));
      float mnew = fmaxf(m_st[rr], mt);
      float alpha = __expf(m_st[rr] - mnew);
      float ps = 0.f;
#pragma unroll
      for (int nt = 0; nt < 8; nt++) {
        float p = __expf(sc[nt][rr] - mnew);
        sc[nt][rr] = p;
        ps += p;
      }
#pragma unroll
      for (int off = 8; off > 0; off >>= 1) ps += __shfl_xor(ps, off);
      m_st[rr] = mnew;
      l_st[rr] = l_st[rr] * alpha + ps;
#pragma unroll
      for (int dt = 0; dt < 4; dt++) O[dt][rr] *= alpha;
#pragma unroll
      for (int nt = 0; nt < 8; nt++)
        Ps[(w * 16 + quad * 4 + rr) * 136 + nt * 16 + l15] = f2b(sc[nt][rr]);
    }
#pragma unroll
    for (int ks = 0; ks < 4; ks++) {
      bf16x8 ap = *(const bf16x8*)(Ps + (w * 16 + l15) * 136 + ks * 32 + quad * 8);
#pragma unroll
      for (int dt = 0; dt < 4; dt++) {
        bf16x8 bv = *(const bf16x8*)(Vts + (dt * 16 + l15) * 136 + ks * 32 + quad * 8);
        O[dt] = __builtin_amdgcn_mfma_f32_16x16x32_bf16(ap, bv, O[dt], 0, 0, 0);
      }
    }
  }
#pragma unroll
  for (int dt = 0; dt < 4; dt++) {
    int col = h * 64 + dt * 16 + l15;
#pragma unroll
    for (int rr = 0; rr < 4; rr++) {
      int row = q0 + w * 16 + quad * 4 + rr;
      ctx[((size_t)b * 512 + row) * 1024 + col] = f2b(O[dt][rr] / l_st[rr]);
    }
  }
}

// ---------------- driver ----------------
extern "C" void kernel_launch(void* const* d_in, const int* in_sizes, int n_in,
                              void* d_out, int out_size, void* d_ws, size_t ws_size,
                              hipStream_t stream) {
  (void)in_sizes; (void)n_in; (void)out_size; (void)ws_size;
  const float* x = (const float*)d_in[0];
  const float* pe = (const float*)d_in[1];
  const float* wq = (const float*)d_in[2];
  const float* bq = (const float*)d_in[3];
  const float* wk = (const float*)d_in[4];
  const float* bk = (const float*)d_in[5];
  const float* wv = (const float*)d_in[6];
  const float* bvv = (const float*)d_in[7];
  const float* wo = (const float*)d_in[8];
  const float* bo = (const float*)d_in[9];
  const float* btab = (const float*)d_in[10];
  const float* w1 = (const float*)d_in[11];
  const float* b1 = (const float*)d_in[12];
  const float* w2 = (const float*)d_in[13];
  const float* b2 = (const float*)d_in[14];
  const float* ln1g = (const float*)d_in[15];
  const float* ln1b = (const float*)d_in[16];
  const float* ln2g = (const float*)d_in[17];
  const float* ln2b = (const float*)d_in[18];

  const int M = 8192, D = 1024, F = 4096, NQKV = 3072;
  char* p = (char*)d_ws;
  float* h = (float*)p;   p += (size_t)M * D * 4;        // 32 MB
  float* o1 = (float*)p;  p += (size_t)M * D * 4;        // 32 MB
  u16* xn = (u16*)p;      p += (size_t)M * D * 2;        // 16 MB
  u16* qkv = (u16*)p;     p += (size_t)M * NQKV * 2;     // 48 MB
  u16* ctx = (u16*)p;     p += (size_t)M * D * 2;        // 16 MB
  u16* mid = qkv;  // aliases qkv..ctx (64 MB); qkv/ctx dead by the time mid is written
  u16* wqkvt = (u16*)p;   p += (size_t)NQKV * D * 2;     // 6 MB
  u16* wto = (u16*)p;     p += (size_t)D * D * 2;        // 2 MB
  u16* wt2 = wqkvt;  // aliases wqkvt+wto (exactly 8 MB); both dead after O-proj
  u16* wt1 = (u16*)p;     p += (size_t)D * F * 2;        // 8 MB
  float* bqkv = (float*)p; p += (size_t)NQKV * 4;        // 12 KB

  addpe_kernel<<<8192, 256, 0, stream>>>(x, pe, h);
  for (int i = 0; i < 6; i++) {
    ln_kernel<<<M, 256, 0, stream>>>(h, ln1g + i * D, ln1b + i * D, xn);
    transpose_kernel<<<dim3(D / 32, D / 32), dim3(32, 8), 0, stream>>>(wq + (size_t)i * D * D, wqkvt, D, D);
    transpose_kernel<<<dim3(D / 32, D / 32), dim3(32, 8), 0, stream>>>(wk + (size_t)i * D * D, wqkvt + (size_t)D * D, D, D);
    transpose_kernel<<<dim3(D / 32, D / 32), dim3(32, 8), 0, stream>>>(wv + (size_t)i * D * D, wqkvt + (size_t)2 * D * D, D, D);
    transpose_kernel<<<dim3(D / 32, D / 32), dim3(32, 8), 0, stream>>>(wo + (size_t)i * D * D, wto, D, D);
    transpose_kernel<<<dim3(F / 32, D / 32), dim3(32, 8), 0, stream>>>(w1 + (size_t)i * D * F, wt1, D, F);
    bias_concat_kernel<<<12, 256, 0, stream>>>(bq + i * D, bk + i * D, bvv + i * D, bqkv);
    // QKV fused: M=8192, N=3072, K=1024 (384 blocks)
    gemm256<0, 256><<<dim3(NQKV / 256, M / 256), 512, 0, stream>>>(xn, wqkvt, bqkv, qkv, nullptr, nullptr, M, NQKV, D);
    attn_mfma<<<dim3(8, 16, 16), 256, 0, stream>>>(qkv, qkv + D, qkv + 2 * D,
                                                   btab + (size_t)i * 1023 * 16, ctx, NQKV);
    // O-proj: N=1024 -> 256M x 128N tile, 256 blocks; o1 = h + ctx@wo + bo
    gemm256<2, 128><<<dim3(D / 128, M / 256), 512, 0, stream>>>(ctx, wto, bo + i * D, nullptr, h, o1, M, D, D);
    transpose_kernel<<<dim3(D / 32, F / 32), dim3(32, 8), 0, stream>>>(w2 + (size_t)i * F * D, wt2, F, D);
    ln_kernel<<<M, 256, 0, stream>>>(o1, ln2g + i * D, ln2b + i * D, xn);
    // FFN1: M=8192, N=4096, K=1024 (512 blocks, fused GELU)
    gemm256<1, 256><<<dim3(F / 256, M / 256), 512, 0, stream>>>(xn, wt1, b1 + i * F, mid, nullptr, nullptr, M, F, D);
    // FFN2: N=1024, K=4096 -> 256M x 128N tile, 256 blocks; h = h + o1 + ffn
    gemm256<3, 128><<<dim3(D / 128, M / 256), 512, 0, stream>>>(mid, wt2, b2 + i * D, nullptr, o1, h, M, D, F);
  }
  copy_kernel<<<8192, 256, 0, stream>>>(h, (float*)d_out);
}